// Round 5
// baseline (841.089 us; speedup 1.0000x reference)
//
#include <hip/hip_runtime.h>
#include <cstdint>
#include <cstddef>

typedef unsigned short ushort_t;
typedef __attribute__((ext_vector_type(8))) __bf16 bf16x8;
typedef __attribute__((ext_vector_type(4))) float f32x4;

#define DEVINL __device__ __forceinline__

DEVINL ushort_t f2bf(float f) {
  union { float f; unsigned u; } v; v.f = f;
  unsigned r = (v.u + 0x7fffu + ((v.u >> 16) & 1u)) >> 16;
  return (ushort_t)r;
}
DEVINL float bf2f(ushort_t u) {
  union { unsigned u; float f; } v; v.u = ((unsigned)u) << 16;
  return v.f;
}

DEVINL float wred_sum(float x) {
#pragma unroll
  for (int o = 32; o > 0; o >>= 1) x += __shfl_xor(x, o, 64);
  return x;
}

// async global->LDS, 16B per lane (global_load_lds_dwordx4)
DEVINL void async16(ushort_t* lds, const ushort_t* g) {
  __builtin_amdgcn_global_load_lds(
      (__attribute__((address_space(1))) const unsigned int*)g,
      (__attribute__((address_space(3))) unsigned int*)lds, 16, 0, 0);
}

template <int CPR>
DEVINL int fswz(int r) {
  if constexpr (CPR == 4) return (r >> 2) & 3;
  else return r & 7;  // CPR==8
}

// ---------------- GroupNorm ----------------
__global__ __launch_bounds__(256) void gn_stats_k(const float* __restrict__ x,
                                                  float* __restrict__ stats) {
  const int bg = blockIdx.x;
  const float4* base = (const float4*)(x + ((size_t)bg << 16));
  float s = 0.f, q = 0.f;
  for (int i = threadIdx.x; i < 16384; i += 256) {
    float4 f = base[i];
    s += f.x + f.y + f.z + f.w;
    q += f.x * f.x + f.y * f.y + f.z * f.z + f.w * f.w;
  }
  s = wred_sum(s);
  q = wred_sum(q);
  __shared__ float rs[4], rq[4];
  const int lane = threadIdx.x & 63, wid = threadIdx.x >> 6;
  if (lane == 0) { rs[wid] = s; rq[wid] = q; }
  __syncthreads();
  if (threadIdx.x == 0) {
    float S = rs[0] + rs[1] + rs[2] + rs[3];
    float Q = rq[0] + rq[1] + rq[2] + rq[3];
    float mean = S * (1.f / 65536.f);
    float var = Q * (1.f / 65536.f) - mean * mean;
    stats[2 * bg] = mean;
    stats[2 * bg + 1] = rsqrtf(var + 1e-5f);
  }
}

__global__ __launch_bounds__(256) void gn_apply_k(const float* __restrict__ x,
                                                  const float* __restrict__ stats,
                                                  const float* __restrict__ gs,
                                                  const float* __restrict__ gb,
                                                  ushort_t* __restrict__ h) {
  __shared__ ushort_t tile[32][33];
  const int bid = blockIdx.x;
  const int b = bid >> 11;
  const int r = bid & 2047;
  const int ct = r >> 7, nt = r & 127;
  const int c0 = ct << 5, n0 = nt << 5;
  const int tx = threadIdx.x & 31, ty = threadIdx.x >> 5;
#pragma unroll
  for (int i = 0; i < 4; ++i) {
    const int c = c0 + ty + i * 8;
    const float mean = stats[2 * (b * 32 + (c >> 4))];
    const float rstd = stats[2 * (b * 32 + (c >> 4)) + 1];
    const float xv = x[(((size_t)b * 512 + c) << 12) + n0 + tx];
    tile[ty + i * 8][tx] = f2bf((xv - mean) * rstd * gs[c] + gb[c]);
  }
  __syncthreads();
#pragma unroll
  for (int i = 0; i < 4; ++i) {
    const int n = n0 + ty + i * 8;
    h[(((size_t)b << 12) + n) * 512 + c0 + tx] = tile[tx][ty + i * 8];
  }
}

// fp32 -> bf16 convert with per-matrix scale (sc folded into wq)
struct Ptr4 { const float* src[4]; float wsc[4]; };
__global__ __launch_bounds__(256) void cvt_all_k(Ptr4 s, ushort_t* __restrict__ dst) {
  const int i = blockIdx.x * 256 + threadIdx.x;
  const int m = i >> 18;
  dst[i] = f2bf(s.src[m][i & 262143] * s.wsc[m]);
}

// ---------------- NT GEMM (QKV + final) ----------------
struct Ptr3 { const float* bias[3]; ushort_t* out[3]; float bs[3]; };

template <int BM, int BN, int BK, int EPI>
__global__ __launch_bounds__(256) void gemm_nt_k(
    const ushort_t* __restrict__ A, int lda, const ushort_t* __restrict__ Bm, int ldb,
    void* __restrict__ Cout, int ldc, const float* __restrict__ bias,
    const float* __restrict__ resid, float scale, int K,
    size_t azs, size_t bzs, size_t czs, Ptr3 p3) {
  constexpr int CPR = BK / 8;
  constexpr int WTM = BM / 2, WTN = BN / 2;
  constexpr int MI = WTM / 16, NI = WTN / 16;
  constexpr int AR = (BM * CPR) / 256;
  constexpr int BR = (BN * CPR) / 256;
  __shared__ ushort_t Als[BM * BK];
  __shared__ ushort_t Bls[BN * BK];
  const int tid = threadIdx.x;
  const int lane = tid & 63;
  const int wid = tid >> 6;
  const int quad = lane >> 4;
  const int r16 = lane & 15;
  const int wm = wid >> 1, wn = wid & 1;
  const int m0 = blockIdx.y * BM;
  const int n0 = blockIdx.x * BN;
  const int zb = blockIdx.z;

  A += azs * zb;
  Bm += bzs * zb;

  f32x4 acc[MI][NI] = {};

  for (int kt = 0; kt < K; kt += BK) {
#pragma unroll
    for (int r = 0; r < AR; ++r) {
      const int s = r * 256 + tid;
      const int row = s / CPR;
      const int q = (s % CPR) ^ fswz<CPR>(row);
      async16(&Als[s << 3], A + (size_t)(m0 + row) * lda + kt + (q << 3));
    }
#pragma unroll
    for (int r = 0; r < BR; ++r) {
      const int s = r * 256 + tid;
      const int row = s / CPR;
      const int q = (s % CPR) ^ fswz<CPR>(row);
      async16(&Bls[s << 3], Bm + (size_t)(n0 + row) * ldb + kt + (q << 3));
    }
    __syncthreads();
#pragma unroll
    for (int kf = 0; kf < BK / 32; ++kf) {
      bf16x8 af[MI], bfr[NI];
#pragma unroll
      for (int mi = 0; mi < MI; ++mi) {
        const int lr = wm * WTM + mi * 16 + r16;
        const int ch = kf * 4 + quad;
        af[mi] = *reinterpret_cast<const bf16x8*>(
            &Als[(lr * CPR + (ch ^ fswz<CPR>(lr))) << 3]);
      }
#pragma unroll
      for (int ni = 0; ni < NI; ++ni) {
        const int lr = wn * WTN + ni * 16 + r16;
        const int ch = kf * 4 + quad;
        bfr[ni] = *reinterpret_cast<const bf16x8*>(
            &Bls[(lr * CPR + (ch ^ fswz<CPR>(lr))) << 3]);
      }
#pragma unroll
      for (int mi = 0; mi < MI; ++mi)
#pragma unroll
        for (int ni = 0; ni < NI; ++ni)
          acc[mi][ni] = __builtin_amdgcn_mfma_f32_16x16x32_bf16(
              af[mi], bfr[ni], acc[mi][ni], 0, 0, 0);
    }
    __syncthreads();
  }

  const int mrow = m0 + wm * WTM;
  const int ncol = n0 + wn * WTN;
  if constexpr (EPI == 2) {  // final: fp32 transposed out + resid + bias
    float* C = (float*)Cout;
#pragma unroll
    for (int ni = 0; ni < NI; ++ni) {
      const int col = ncol + ni * 16 + r16;
      const float bvv = bias[col];
#pragma unroll
      for (int mi = 0; mi < MI; ++mi) {
        const int rowb = mrow + mi * 16 + quad * 4;
        const int bb = rowb >> 12;
        const int nl = rowb & 4095;
        const size_t base = (((size_t)bb * 512 + col) << 12) + nl;
        const float4 rv = *(const float4*)&resid[base];
        float4 ov;
        ov.x = rv.x + acc[mi][ni][0] + bvv;
        ov.y = rv.y + acc[mi][ni][1] + bvv;
        ov.z = rv.z + acc[mi][ni][2] + bvv;
        ov.w = rv.w + acc[mi][ni][3] + bvv;
        *(float4*)&C[base] = ov;
      }
    }
  } else {  // EPI == 3: QKV, z picks weight/bias/out; z==2 (V) transposed
    const float* bz = p3.bias[zb];
    const float bsc = p3.bs[zb];
    ushort_t* O = p3.out[zb];
    if (zb < 2) {
#pragma unroll
      for (int ni = 0; ni < NI; ++ni) {
        const int col = ncol + ni * 16 + r16;
        const float bvv = bz[col] * bsc;
#pragma unroll
        for (int mi = 0; mi < MI; ++mi) {
          const int rowb = mrow + mi * 16 + quad * 4;
#pragma unroll
          for (int rr = 0; rr < 4; ++rr)
            O[(size_t)(rowb + rr) * 512 + col] = f2bf(acc[mi][ni][rr] + bvv);
        }
      }
    } else {
#pragma unroll
      for (int ni = 0; ni < NI; ++ni) {
        const int col = ncol + ni * 16 + r16;
        const float bvv = bz[col];
#pragma unroll
        for (int mi = 0; mi < MI; ++mi) {
          const int rowb = mrow + mi * 16 + quad * 4;
          const int bb = rowb >> 12;
          const int nn = rowb & 4095;
          ushort4 pk;
          pk.x = f2bf(acc[mi][ni][0] + bvv);
          pk.y = f2bf(acc[mi][ni][1] + bvv);
          pk.z = f2bf(acc[mi][ni][2] + bvv);
          pk.w = f2bf(acc[mi][ni][3] + bvv);
          *(ushort4*)&O[(((size_t)bb * 512 + col) << 12) + nn] = pk;
        }
      }
    }
  }
}

// ---------------- Flash attention v3: kv-split-2 + 2 blocks/CU ----------------
// grid (64 qtiles, 4 batches, 2 kv-halves), 512 thr (8 waves).
// Block: 64 Q-rows x 2048 kv (its half) as 16 tiles of 128 kv.
// LDS 66 KB: K/V ping-pong 2x16KB, Q-chunk ping-pong 2x8KB, P 16KB, red 2KB
//   -> 2 blocks/CU; __launch_bounds__(512,4) caps VGPR 128 -> 4 waves/SIMD.
// Waves wm(2: 32-row bands) x wk(4). S: wave 32 rows x 32 kv (af2/bf2).
// PV: per phase 128-D chunk x 64 kv; wave 32 rows x 32 D (pa2/vb2).
// Single barrier per phase; stage next phase right after barrier (loads in
// flight during compute). Outputs partial O (l-normalized) + m,l per row.
#define FLASH_LDS_BYTES 67584
__global__ __launch_bounds__(512, 4) void flash_k(
    const ushort_t* __restrict__ Qb, const ushort_t* __restrict__ Kb,
    const ushort_t* __restrict__ Vtb, ushort_t* __restrict__ Opart,
    float* __restrict__ Mp, float* __restrict__ Lp) {
  extern __shared__ ushort_t lds[];
  // buffers (ushort offsets): buf0 0, buf1 8192, Q0 16384, Q1 20480, Pl 24576
  ushort_t* Pl = lds + 24576;            // [64][16ch of 8] swizzled, 16 KB
  float* redmax = (float*)(lds + 32768); // [64][4]
  float* redsum = redmax + 256;          // [64][4]

  const int tid = threadIdx.x;
  const int lane = tid & 63;
  const int wid = tid >> 6;
  const int quad = lane >> 4;
  const int r16 = lane & 15;
  const int wm = wid >> 2;   // 0..1
  const int wk = wid & 3;    // 0..3
  const int qb0 = blockIdx.x * 64;
  const int b = blockIdx.y;
  const int z = blockIdx.z;  // kv half
  const size_t bofs = (size_t)b * 4096 * 512;
  const ushort_t* qg = Qb + bofs + (size_t)qb0 * 512;
  const ushort_t* kg = Kb + bofs + (size_t)(z * 2048) * 512;
  const ushort_t* vg = Vtb + bofs + z * 2048;

  auto stage_K = [&](int bf_, int t, int p) {  // 16 KB: [128 kv][8 ch]
    ushort_t* dst = lds + bf_ * 8192;
    const ushort_t* src = kg + (size_t)(t * 128) * 512 + p * 64;
#pragma unroll
    for (int r = 0; r < 2; ++r) {
      const int s = r * 512 + tid;
      const int row = s >> 3, c = s & 7;
      async16(dst + ((size_t)s << 3), src + (size_t)row * 512 + ((c ^ (row & 7)) << 3));
    }
  };
  auto stage_Q = [&](int slot, int p) {  // 8 KB: [64 rows][8 ch]
    ushort_t* dst = lds + 16384 + slot * 4096;
    const int row = tid >> 3, c = tid & 7;
    async16(dst + ((size_t)tid << 3),
            qg + (size_t)row * 512 + p * 64 + ((c ^ (row & 7)) << 3));
  };
  auto stage_V = [&](int bf_, int t, int p) {  // 16 KB: [128 Drows][8 ch of 8kv]
    ushort_t* dst = lds + bf_ * 8192;
    const int dc = p >> 1, kvc = p & 1;
    const ushort_t* src = vg + t * 128 + kvc * 64;
#pragma unroll
    for (int r = 0; r < 2; ++r) {
      const int s = r * 512 + tid;
      const int row = s >> 3, c = s & 7;
      async16(dst + ((size_t)s << 3),
              src + (size_t)(dc * 128 + row) * 4096 + ((c ^ (row & 7)) << 3));
    }
  };

  f32x4 accO[2][8] = {};  // [mi][dc*2+ni]
  float m_i[2][4], l_i[2][4];
#pragma unroll
  for (int mi = 0; mi < 2; ++mi)
#pragma unroll
    for (int rr = 0; rr < 4; ++rr) { m_i[mi][rr] = -3.0e38f; l_i[mi][rr] = 0.f; }

  stage_K(0, 0, 0);
  stage_Q(0, 0);
  int buf = 0, qs = 0;

  for (int t = 0; t < 16; ++t) {
    f32x4 accS[2][2] = {};
    // ---- S phases: S(64x128) over D=512 in 8 chunks of 64
    for (int p = 0; p < 8; ++p) {
      __syncthreads();
      if (p < 7) { stage_K(buf ^ 1, t, p + 1); stage_Q(qs ^ 1, p + 1); }
      else stage_V(buf ^ 1, t, 0);
      const ushort_t* kb_ = lds + buf * 8192;
      const ushort_t* qb_ = lds + 16384 + qs * 4096;
#pragma unroll
      for (int kc = 0; kc < 2; ++kc) {
        bf16x8 af[2], bfv[2];
#pragma unroll
        for (int mi = 0; mi < 2; ++mi) {
          const int row = wm * 32 + mi * 16 + r16;
          af[mi] = *(const bf16x8*)&qb_[(row * 8 + ((kc * 4 + quad) ^ (row & 7))) << 3];
        }
#pragma unroll
        for (int ni = 0; ni < 2; ++ni) {
          const int kr = wk * 32 + ni * 16 + r16;
          bfv[ni] = *(const bf16x8*)&kb_[(kr * 8 + ((kc * 4 + quad) ^ (kr & 7))) << 3];
        }
#pragma unroll
        for (int mi = 0; mi < 2; ++mi)
#pragma unroll
          for (int ni = 0; ni < 2; ++ni)
            accS[mi][ni] = __builtin_amdgcn_mfma_f32_16x16x32_bf16(
                af[mi], bfv[ni], accS[mi][ni], 0, 0, 0);
      }
      buf ^= 1;
      if (p < 7) qs ^= 1;
    }
    // ---- online softmax over the 128-kv tile
    float mnew[2][4], alpha[2][4];
#pragma unroll
    for (int mi = 0; mi < 2; ++mi)
#pragma unroll
      for (int rr = 0; rr < 4; ++rr) {
        float mx = fmaxf(accS[mi][0][rr], accS[mi][1][rr]);
#pragma unroll
        for (int o = 8; o >= 1; o >>= 1) mx = fmaxf(mx, __shfl_xor(mx, o, 64));
        if (r16 == 0)
          redmax[(wm * 32 + mi * 16 + quad * 4 + rr) * 4 + wk] = mx;
      }
    __syncthreads();
#pragma unroll
    for (int mi = 0; mi < 2; ++mi)
#pragma unroll
      for (int rr = 0; rr < 4; ++rr) {
        const int row = wm * 32 + mi * 16 + quad * 4 + rr;
        float mx = fmaxf(fmaxf(redmax[row * 4], redmax[row * 4 + 1]),
                         fmaxf(redmax[row * 4 + 2], redmax[row * 4 + 3]));
        mx = fmaxf(mx, m_i[mi][rr]);
        mnew[mi][rr] = mx;
        alpha[mi][rr] = __expf(m_i[mi][rr] - mx);
        m_i[mi][rr] = mx;
      }
#pragma unroll
    for (int mi = 0; mi < 2; ++mi)
#pragma unroll
      for (int rr = 0; rr < 4; ++rr) {
        const int row = wm * 32 + mi * 16 + quad * 4 + rr;
        float ps = 0.f;
#pragma unroll
        for (int ni = 0; ni < 2; ++ni) {
          float e = __expf(accS[mi][ni][rr] - mnew[mi][rr]);
          ps += e;
          const int col = wk * 32 + ni * 16 + r16;
          Pl[((row * 16 + ((col >> 3) ^ (row & 15))) << 3) + (col & 7)] = f2bf(e);
        }
#pragma unroll
        for (int o = 8; o >= 1; o >>= 1) ps += __shfl_xor(ps, o, 64);
        if (r16 == 0) redsum[row * 4 + wk] = ps;
      }
    __syncthreads();  // publishes P/redsum; drains V(0) loads
#pragma unroll
    for (int mi = 0; mi < 2; ++mi)
#pragma unroll
      for (int rr = 0; rr < 4; ++rr) {
        const int row = wm * 32 + mi * 16 + quad * 4 + rr;
        const float s = redsum[row * 4] + redsum[row * 4 + 1] +
                        redsum[row * 4 + 2] + redsum[row * 4 + 3];
        l_i[mi][rr] = l_i[mi][rr] * alpha[mi][rr] + s;
      }
#pragma unroll
    for (int mi = 0; mi < 2; ++mi)
#pragma unroll
      for (int ni = 0; ni < 8; ++ni)
#pragma unroll
        for (int rr = 0; rr < 4; ++rr)
          accO[mi][ni][rr] *= alpha[mi][rr];
    // ---- PV phases: 8 of (128-D chunk x 64 kv)
    for (int p = 0; p < 8; ++p) {
      if (p) __syncthreads();
      if (p < 7) stage_V(buf ^ 1, t, p + 1);
      else if (t < 15) { stage_K(buf ^ 1, t + 1, 0); stage_Q(qs ^ 1, 0); }
      const ushort_t* vb_ = lds + buf * 8192;
      const int dc = p >> 1, kvc = p & 1;
#pragma unroll
      for (int kc = 0; kc < 2; ++kc) {
        bf16x8 pa[2], vv[2];
#pragma unroll
        for (int mi = 0; mi < 2; ++mi) {
          const int row = wm * 32 + mi * 16 + r16;
          pa[mi] = *(const bf16x8*)
              &Pl[(row * 16 + ((kvc * 8 + kc * 4 + quad) ^ (row & 15))) << 3];
        }
#pragma unroll
        for (int ni = 0; ni < 2; ++ni) {
          const int dr = wk * 32 + ni * 16 + r16;
          vv[ni] = *(const bf16x8*)&vb_[(dr * 8 + ((kc * 4 + quad) ^ (dr & 7))) << 3];
        }
#pragma unroll
        for (int mi = 0; mi < 2; ++mi)
#pragma unroll
          for (int ni = 0; ni < 2; ++ni)
            accO[mi][dc * 2 + ni] = __builtin_amdgcn_mfma_f32_16x16x32_bf16(
                pa[mi], vv[ni], accO[mi][dc * 2 + ni], 0, 0, 0);
      }
      buf ^= 1;
    }
    qs ^= 1;
  }
  // epilogue: partial O (normalized by l), plus m,l
  ushort_t* Op = Opart + (size_t)z * 4 * 4096 * 512 + bofs;
#pragma unroll
  for (int mi = 0; mi < 2; ++mi)
#pragma unroll
    for (int rr = 0; rr < 4; ++rr) {
      const float inv = 1.f / l_i[mi][rr];
      const int row = qb0 + wm * 32 + mi * 16 + quad * 4 + rr;
      ushort_t* op = Op + (size_t)row * 512;
#pragma unroll
      for (int dc = 0; dc < 4; ++dc)
#pragma unroll
        for (int ni = 0; ni < 2; ++ni)
          op[dc * 128 + wk * 32 + ni * 16 + r16] =
              f2bf(accO[mi][dc * 2 + ni][rr] * inv);
      if (wk == 0 && r16 == 0) {
        Mp[z * 16384 + b * 4096 + row] = m_i[mi][rr];
        Lp[z * 16384 + b * 4096 + row] = l_i[mi][rr];
      }
    }
}

// merge the two kv-half partials: h = (w0*O0 + w1*O1), w_i = l_i e^{m_i-m}/Z
__global__ __launch_bounds__(128) void merge_k(
    const ushort_t* __restrict__ Opart, const float* __restrict__ Mp,
    const float* __restrict__ Lp, ushort_t* __restrict__ h) {
  const int row = blockIdx.x;  // b*4096+n, 0..16383
  const float m0 = Mp[row], m1 = Mp[16384 + row];
  const float l0 = Lp[row], l1 = Lp[16384 + row];
  const float mm = fmaxf(m0, m1);
  float w0 = __expf(m0 - mm) * l0, w1 = __expf(m1 - mm) * l1;
  const float inv = 1.f / (w0 + w1);
  w0 *= inv; w1 *= inv;
  const ushort4* a = (const ushort4*)(Opart + (size_t)row * 512);
  const ushort4* bb = (const ushort4*)(Opart + (size_t)(16384 + row) * 512);
  ushort4* o = (ushort4*)(h + (size_t)row * 512);
  const int t = threadIdx.x;
  ushort4 ua = a[t], ub = bb[t];
  ushort4 r;
  r.x = f2bf(bf2f(ua.x) * w0 + bf2f(ub.x) * w1);
  r.y = f2bf(bf2f(ua.y) * w0 + bf2f(ub.y) * w1);
  r.z = f2bf(bf2f(ua.z) * w0 + bf2f(ub.z) * w1);
  r.w = f2bf(bf2f(ua.w) * w0 + bf2f(ub.w) * w1);
  o[t] = r;
}

extern "C" void kernel_launch(void* const* d_in, const int* in_sizes, int n_in,
                              void* d_out, int out_size, void* d_ws, size_t ws_size,
                              hipStream_t stream) {
  const float* x  = (const float*)d_in[0];
  const float* gs = (const float*)d_in[1];
  const float* gb = (const float*)d_in[2];
  const float* wq = (const float*)d_in[3];
  const float* bq = (const float*)d_in[4];
  const float* wk = (const float*)d_in[5];
  const float* bk = (const float*)d_in[6];
  const float* wv = (const float*)d_in[7];
  const float* bv = (const float*)d_in[8];
  const float* wo = (const float*)d_in[9];
  const float* bo = (const float*)d_in[10];
  float* out = (float*)d_out;

  const size_t HNC = (size_t)4 * 4096 * 512;
  char* w = (char*)d_ws;
  float* stats  = (float*)w;    w += 4096;
  ushort_t* wb  = (ushort_t*)w; w += (size_t)4 * 262144 * 2;
  ushort_t* h   = (ushort_t*)w; w += HNC * 2;  // GN out; reused as merged O
  ushort_t* q   = (ushort_t*)w; w += HNC * 2;
  ushort_t* kk  = (ushort_t*)w; w += HNC * 2;
  ushort_t* vt  = (ushort_t*)w; w += HNC * 2;  // V transposed [B,C,N]
  ushort_t* op  = (ushort_t*)w; w += 2 * HNC * 2;  // partial O, 2 kv-halves
  float* Mp     = (float*)w;    w += 2 * 16384 * 4;
  float* Lp     = (float*)w;    w += 2 * 16384 * 4;

  const float sc = 0.044194173824159216f;  // 512^-0.5, folded into wq/bq

  hipFuncSetAttribute((const void*)flash_k,
                      hipFuncAttributeMaxDynamicSharedMemorySize, FLASH_LDS_BYTES);

  gn_stats_k<<<128, 256, 0, stream>>>(x, stats);
  gn_apply_k<<<8192, 256, 0, stream>>>(x, stats, gs, gb, h);
  Ptr4 wsrc;
  wsrc.src[0] = wq; wsrc.src[1] = wk; wsrc.src[2] = wv; wsrc.src[3] = wo;
  wsrc.wsc[0] = sc; wsrc.wsc[1] = 1.f; wsrc.wsc[2] = 1.f; wsrc.wsc[3] = 1.f;
  cvt_all_k<<<4096, 256, 0, stream>>>(wsrc, wb);

  Ptr3 qkv;
  qkv.bias[0] = bq; qkv.bias[1] = bk; qkv.bias[2] = bv;
  qkv.out[0] = q; qkv.out[1] = kk; qkv.out[2] = vt;
  qkv.bs[0] = sc; qkv.bs[1] = 1.f; qkv.bs[2] = 1.f;
  gemm_nt_k<128, 128, 32, 3><<<dim3(4, 128, 3), 256, 0, stream>>>(
      h, 512, wb, 512, nullptr, 0, nullptr, nullptr, 1.f, 512,
      0, 262144, 0, qkv);

  flash_k<<<dim3(64, 4, 2), 512, FLASH_LDS_BYTES, stream>>>(q, kk, vt, op, Mp, Lp);
  merge_k<<<16384, 128, 0, stream>>>(op, Mp, Lp, h);

  Ptr3 e0{};
  gemm_nt_k<128, 128, 32, 2><<<dim3(4, 128, 1), 256, 0, stream>>>(
      h, 512, wb + (size_t)3 * 262144, 512, out, 512, bo, x, 1.f, 512,
      0, 0, 0, e0);
}

// Round 6
// 579.256 us; speedup vs baseline: 1.4520x; 1.4520x over previous
//
#include <hip/hip_runtime.h>
#include <cstdint>
#include <cstddef>

typedef unsigned short ushort_t;
typedef __attribute__((ext_vector_type(8))) __bf16 bf16x8;
typedef __attribute__((ext_vector_type(4))) float f32x4;

#define DEVINL __device__ __forceinline__

DEVINL ushort_t f2bf(float f) {
  union { float f; unsigned u; } v; v.f = f;
  unsigned r = (v.u + 0x7fffu + ((v.u >> 16) & 1u)) >> 16;
  return (ushort_t)r;
}
DEVINL float bf2f(ushort_t u) {
  union { unsigned u; float f; } v; v.u = ((unsigned)u) << 16;
  return v.f;
}

DEVINL float wred_sum(float x) {
#pragma unroll
  for (int o = 32; o > 0; o >>= 1) x += __shfl_xor(x, o, 64);
  return x;
}

// async global->LDS, 16B per lane (global_load_lds_dwordx4)
DEVINL void async16(ushort_t* lds, const ushort_t* g) {
  __builtin_amdgcn_global_load_lds(
      (__attribute__((address_space(1))) const unsigned int*)g,
      (__attribute__((address_space(3))) unsigned int*)lds, 16, 0, 0);
}

template <int CPR>
DEVINL int fswz(int r) {
  if constexpr (CPR == 4) return (r >> 2) & 3;
  else return r & 7;  // CPR==8
}

// ---------------- GroupNorm ----------------
__global__ __launch_bounds__(256) void gn_stats_k(const float* __restrict__ x,
                                                  float* __restrict__ stats) {
  const int bg = blockIdx.x;
  const float4* base = (const float4*)(x + ((size_t)bg << 16));
  float s = 0.f, q = 0.f;
  for (int i = threadIdx.x; i < 16384; i += 256) {
    float4 f = base[i];
    s += f.x + f.y + f.z + f.w;
    q += f.x * f.x + f.y * f.y + f.z * f.z + f.w * f.w;
  }
  s = wred_sum(s);
  q = wred_sum(q);
  __shared__ float rs[4], rq[4];
  const int lane = threadIdx.x & 63, wid = threadIdx.x >> 6;
  if (lane == 0) { rs[wid] = s; rq[wid] = q; }
  __syncthreads();
  if (threadIdx.x == 0) {
    float S = rs[0] + rs[1] + rs[2] + rs[3];
    float Q = rq[0] + rq[1] + rq[2] + rq[3];
    float mean = S * (1.f / 65536.f);
    float var = Q * (1.f / 65536.f) - mean * mean;
    stats[2 * bg] = mean;
    stats[2 * bg + 1] = rsqrtf(var + 1e-5f);
  }
}

__global__ __launch_bounds__(256) void gn_apply_k(const float* __restrict__ x,
                                                  const float* __restrict__ stats,
                                                  const float* __restrict__ gs,
                                                  const float* __restrict__ gb,
                                                  ushort_t* __restrict__ h) {
  __shared__ ushort_t tile[32][33];
  const int bid = blockIdx.x;
  const int b = bid >> 11;
  const int r = bid & 2047;
  const int ct = r >> 7, nt = r & 127;
  const int c0 = ct << 5, n0 = nt << 5;
  const int tx = threadIdx.x & 31, ty = threadIdx.x >> 5;
#pragma unroll
  for (int i = 0; i < 4; ++i) {
    const int c = c0 + ty + i * 8;
    const float mean = stats[2 * (b * 32 + (c >> 4))];
    const float rstd = stats[2 * (b * 32 + (c >> 4)) + 1];
    const float xv = x[(((size_t)b * 512 + c) << 12) + n0 + tx];
    tile[ty + i * 8][tx] = f2bf((xv - mean) * rstd * gs[c] + gb[c]);
  }
  __syncthreads();
#pragma unroll
  for (int i = 0; i < 4; ++i) {
    const int n = n0 + ty + i * 8;
    h[(((size_t)b << 12) + n) * 512 + c0 + tx] = tile[tx][ty + i * 8];
  }
}

// fp32 -> bf16 convert with per-matrix scale (sc folded into wq)
struct Ptr4 { const float* src[4]; float wsc[4]; };
__global__ __launch_bounds__(256) void cvt_all_k(Ptr4 s, ushort_t* __restrict__ dst) {
  const int i = blockIdx.x * 256 + threadIdx.x;
  const int m = i >> 18;
  dst[i] = f2bf(s.src[m][i & 262143] * s.wsc[m]);
}

// ---------------- NT GEMM (QKV + final) ----------------
struct Ptr3 { const float* bias[3]; ushort_t* out[3]; float bs[3]; };

template <int BM, int BN, int BK, int EPI>
__global__ __launch_bounds__(256) void gemm_nt_k(
    const ushort_t* __restrict__ A, int lda, const ushort_t* __restrict__ Bm, int ldb,
    void* __restrict__ Cout, int ldc, const float* __restrict__ bias,
    const float* __restrict__ resid, float scale, int K,
    size_t azs, size_t bzs, size_t czs, Ptr3 p3) {
  constexpr int CPR = BK / 8;
  constexpr int WTM = BM / 2, WTN = BN / 2;
  constexpr int MI = WTM / 16, NI = WTN / 16;
  constexpr int AR = (BM * CPR) / 256;
  constexpr int BR = (BN * CPR) / 256;
  __shared__ ushort_t Als[BM * BK];
  __shared__ ushort_t Bls[BN * BK];
  const int tid = threadIdx.x;
  const int lane = tid & 63;
  const int wid = tid >> 6;
  const int quad = lane >> 4;
  const int r16 = lane & 15;
  const int wm = wid >> 1, wn = wid & 1;
  const int m0 = blockIdx.y * BM;
  const int n0 = blockIdx.x * BN;
  const int zb = blockIdx.z;

  A += azs * zb;
  Bm += bzs * zb;

  f32x4 acc[MI][NI] = {};

  for (int kt = 0; kt < K; kt += BK) {
#pragma unroll
    for (int r = 0; r < AR; ++r) {
      const int s = r * 256 + tid;
      const int row = s / CPR;
      const int q = (s % CPR) ^ fswz<CPR>(row);
      async16(&Als[s << 3], A + (size_t)(m0 + row) * lda + kt + (q << 3));
    }
#pragma unroll
    for (int r = 0; r < BR; ++r) {
      const int s = r * 256 + tid;
      const int row = s / CPR;
      const int q = (s % CPR) ^ fswz<CPR>(row);
      async16(&Bls[s << 3], Bm + (size_t)(n0 + row) * ldb + kt + (q << 3));
    }
    __syncthreads();
#pragma unroll
    for (int kf = 0; kf < BK / 32; ++kf) {
      bf16x8 af[MI], bfr[NI];
#pragma unroll
      for (int mi = 0; mi < MI; ++mi) {
        const int lr = wm * WTM + mi * 16 + r16;
        const int ch = kf * 4 + quad;
        af[mi] = *reinterpret_cast<const bf16x8*>(
            &Als[(lr * CPR + (ch ^ fswz<CPR>(lr))) << 3]);
      }
#pragma unroll
      for (int ni = 0; ni < NI; ++ni) {
        const int lr = wn * WTN + ni * 16 + r16;
        const int ch = kf * 4 + quad;
        bfr[ni] = *reinterpret_cast<const bf16x8*>(
            &Bls[(lr * CPR + (ch ^ fswz<CPR>(lr))) << 3]);
      }
#pragma unroll
      for (int mi = 0; mi < MI; ++mi)
#pragma unroll
        for (int ni = 0; ni < NI; ++ni)
          acc[mi][ni] = __builtin_amdgcn_mfma_f32_16x16x32_bf16(
              af[mi], bfr[ni], acc[mi][ni], 0, 0, 0);
    }
    __syncthreads();
  }

  const int mrow = m0 + wm * WTM;
  const int ncol = n0 + wn * WTN;
  if constexpr (EPI == 2) {  // final: fp32 transposed out + resid + bias
    float* C = (float*)Cout;
#pragma unroll
    for (int ni = 0; ni < NI; ++ni) {
      const int col = ncol + ni * 16 + r16;
      const float bvv = bias[col];
#pragma unroll
      for (int mi = 0; mi < MI; ++mi) {
        const int rowb = mrow + mi * 16 + quad * 4;
        const int bb = rowb >> 12;
        const int nl = rowb & 4095;
        const size_t base = (((size_t)bb * 512 + col) << 12) + nl;
        const float4 rv = *(const float4*)&resid[base];
        float4 ov;
        ov.x = rv.x + acc[mi][ni][0] + bvv;
        ov.y = rv.y + acc[mi][ni][1] + bvv;
        ov.z = rv.z + acc[mi][ni][2] + bvv;
        ov.w = rv.w + acc[mi][ni][3] + bvv;
        *(float4*)&C[base] = ov;
      }
    }
  } else {  // EPI == 3: QKV, z picks weight/bias/out; z==2 (V) transposed
    const float* bz = p3.bias[zb];
    const float bsc = p3.bs[zb];
    ushort_t* O = p3.out[zb];
    if (zb < 2) {
#pragma unroll
      for (int ni = 0; ni < NI; ++ni) {
        const int col = ncol + ni * 16 + r16;
        const float bvv = bz[col] * bsc;
#pragma unroll
        for (int mi = 0; mi < MI; ++mi) {
          const int rowb = mrow + mi * 16 + quad * 4;
#pragma unroll
          for (int rr = 0; rr < 4; ++rr)
            O[(size_t)(rowb + rr) * 512 + col] = f2bf(acc[mi][ni][rr] + bvv);
        }
      }
    } else {
#pragma unroll
      for (int ni = 0; ni < NI; ++ni) {
        const int col = ncol + ni * 16 + r16;
        const float bvv = bz[col];
#pragma unroll
        for (int mi = 0; mi < MI; ++mi) {
          const int rowb = mrow + mi * 16 + quad * 4;
          const int bb = rowb >> 12;
          const int nn = rowb & 4095;
          ushort4 pk;
          pk.x = f2bf(acc[mi][ni][0] + bvv);
          pk.y = f2bf(acc[mi][ni][1] + bvv);
          pk.z = f2bf(acc[mi][ni][2] + bvv);
          pk.w = f2bf(acc[mi][ni][3] + bvv);
          *(ushort4*)&O[(((size_t)bb * 512 + col) << 12) + nn] = pk;
        }
      }
    }
  }
}

// ---------------- Flash attention v3.1: kv-split-2, spill-free ----------------
// grid (64 qtiles, 4 batches, 2 kv-halves), 512 thr (8 waves).
// LDS 66 KB -> 2 blocks/CU if VGPR<=128. NO forced VGPR cap (launch_bounds(512)
// only): if pressure lands <=128 we get 4 waves/SIMD; if slightly over we
// degrade to 1 block/CU instead of spilling (R5 lesson: the (512,4) cap caused
// accumulator spill -> 1 GB scratch traffic).
// Softmax fused scalar pass: no mnew/alpha arrays (l_i *= alpha now, += s after
// barrier) -> ~16 fewer live VGPRs.
#define FLASH_LDS_BYTES 67584
__global__ __launch_bounds__(512) void flash_k(
    const ushort_t* __restrict__ Qb, const ushort_t* __restrict__ Kb,
    const ushort_t* __restrict__ Vtb, ushort_t* __restrict__ Opart,
    float* __restrict__ Mp, float* __restrict__ Lp) {
  extern __shared__ ushort_t lds[];
  // buffers (ushort offsets): buf0 0, buf1 8192, Q0 16384, Q1 20480, Pl 24576
  ushort_t* Pl = lds + 24576;            // [64][16ch of 8] swizzled, 16 KB
  float* redmax = (float*)(lds + 32768); // [64][4]
  float* redsum = redmax + 256;          // [64][4]

  const int tid = threadIdx.x;
  const int lane = tid & 63;
  const int wid = tid >> 6;
  const int quad = lane >> 4;
  const int r16 = lane & 15;
  const int wm = wid >> 2;   // 0..1
  const int wk = wid & 3;    // 0..3
  const int qb0 = blockIdx.x * 64;
  const int b = blockIdx.y;
  const int z = blockIdx.z;  // kv half
  const size_t bofs = (size_t)b * 4096 * 512;
  const ushort_t* qg = Qb + bofs + (size_t)qb0 * 512;
  const ushort_t* kg = Kb + bofs + (size_t)(z * 2048) * 512;
  const ushort_t* vg = Vtb + bofs + z * 2048;

  auto stage_K = [&](int bf_, int t, int p) {  // 16 KB: [128 kv][8 ch]
    ushort_t* dst = lds + bf_ * 8192;
    const ushort_t* src = kg + (size_t)(t * 128) * 512 + p * 64;
#pragma unroll
    for (int r = 0; r < 2; ++r) {
      const int s = r * 512 + tid;
      const int row = s >> 3, c = s & 7;
      async16(dst + ((size_t)s << 3), src + (size_t)row * 512 + ((c ^ (row & 7)) << 3));
    }
  };
  auto stage_Q = [&](int slot, int p) {  // 8 KB: [64 rows][8 ch]
    ushort_t* dst = lds + 16384 + slot * 4096;
    const int row = tid >> 3, c = tid & 7;
    async16(dst + ((size_t)tid << 3),
            qg + (size_t)row * 512 + p * 64 + ((c ^ (row & 7)) << 3));
  };
  auto stage_V = [&](int bf_, int t, int p) {  // 16 KB: [128 Drows][8 ch of 8kv]
    ushort_t* dst = lds + bf_ * 8192;
    const int dc = p >> 1, kvc = p & 1;
    const ushort_t* src = vg + t * 128 + kvc * 64;
#pragma unroll
    for (int r = 0; r < 2; ++r) {
      const int s = r * 512 + tid;
      const int row = s >> 3, c = s & 7;
      async16(dst + ((size_t)s << 3),
              src + (size_t)(dc * 128 + row) * 4096 + ((c ^ (row & 7)) << 3));
    }
  };

  f32x4 accO[2][8] = {};  // [mi][dc*2+ni]
  float m_i[2][4], l_i[2][4];
#pragma unroll
  for (int mi = 0; mi < 2; ++mi)
#pragma unroll
    for (int rr = 0; rr < 4; ++rr) { m_i[mi][rr] = -3.0e38f; l_i[mi][rr] = 0.f; }

  stage_K(0, 0, 0);
  stage_Q(0, 0);
  int buf = 0, qs = 0;

  for (int t = 0; t < 16; ++t) {
    f32x4 accS[2][2] = {};
    // ---- S phases: S(64x128) over D=512 in 8 chunks of 64
    for (int p = 0; p < 8; ++p) {
      __syncthreads();
      if (p < 7) { stage_K(buf ^ 1, t, p + 1); stage_Q(qs ^ 1, p + 1); }
      else stage_V(buf ^ 1, t, 0);
      const ushort_t* kb_ = lds + buf * 8192;
      const ushort_t* qb_ = lds + 16384 + qs * 4096;
#pragma unroll
      for (int kc = 0; kc < 2; ++kc) {
        bf16x8 af[2], bfv[2];
#pragma unroll
        for (int mi = 0; mi < 2; ++mi) {
          const int row = wm * 32 + mi * 16 + r16;
          af[mi] = *(const bf16x8*)&qb_[(row * 8 + ((kc * 4 + quad) ^ (row & 7))) << 3];
        }
#pragma unroll
        for (int ni = 0; ni < 2; ++ni) {
          const int kr = wk * 32 + ni * 16 + r16;
          bfv[ni] = *(const bf16x8*)&kb_[(kr * 8 + ((kc * 4 + quad) ^ (kr & 7))) << 3];
        }
#pragma unroll
        for (int mi = 0; mi < 2; ++mi)
#pragma unroll
          for (int ni = 0; ni < 2; ++ni)
            accS[mi][ni] = __builtin_amdgcn_mfma_f32_16x16x32_bf16(
                af[mi], bfv[ni], accS[mi][ni], 0, 0, 0);
      }
      buf ^= 1;
      if (p < 7) qs ^= 1;
    }
    // ---- online softmax over the 128-kv tile (fused, register-lean)
#pragma unroll
    for (int mi = 0; mi < 2; ++mi)
#pragma unroll
      for (int rr = 0; rr < 4; ++rr) {
        float mx = fmaxf(accS[mi][0][rr], accS[mi][1][rr]);
#pragma unroll
        for (int o = 8; o >= 1; o >>= 1) mx = fmaxf(mx, __shfl_xor(mx, o, 64));
        if (r16 == 0)
          redmax[(wm * 32 + mi * 16 + quad * 4 + rr) * 4 + wk] = mx;
      }
    __syncthreads();
#pragma unroll
    for (int mi = 0; mi < 2; ++mi)
#pragma unroll
      for (int rr = 0; rr < 4; ++rr) {
        const int row = wm * 32 + mi * 16 + quad * 4 + rr;
        float mx = fmaxf(fmaxf(redmax[row * 4], redmax[row * 4 + 1]),
                         fmaxf(redmax[row * 4 + 2], redmax[row * 4 + 3]));
        mx = fmaxf(mx, m_i[mi][rr]);
        const float alpha = __expf(m_i[mi][rr] - mx);
        m_i[mi][rr] = mx;
        l_i[mi][rr] *= alpha;
#pragma unroll
        for (int ni = 0; ni < 8; ++ni) accO[mi][ni][rr] *= alpha;
        float ps = 0.f;
#pragma unroll
        for (int ni = 0; ni < 2; ++ni) {
          const float e = __expf(accS[mi][ni][rr] - mx);
          ps += e;
          const int col = wk * 32 + ni * 16 + r16;
          Pl[((row * 16 + ((col >> 3) ^ (row & 15))) << 3) + (col & 7)] = f2bf(e);
        }
#pragma unroll
        for (int o = 8; o >= 1; o >>= 1) ps += __shfl_xor(ps, o, 64);
        if (r16 == 0) redsum[row * 4 + wk] = ps;
      }
    __syncthreads();  // publishes P/redsum; drains V(0) loads
#pragma unroll
    for (int mi = 0; mi < 2; ++mi)
#pragma unroll
      for (int rr = 0; rr < 4; ++rr) {
        const int row = wm * 32 + mi * 16 + quad * 4 + rr;
        l_i[mi][rr] += redsum[row * 4] + redsum[row * 4 + 1] +
                       redsum[row * 4 + 2] + redsum[row * 4 + 3];
      }
    // ---- PV phases: 8 of (128-D chunk x 64 kv)
    for (int p = 0; p < 8; ++p) {
      if (p) __syncthreads();
      if (p < 7) stage_V(buf ^ 1, t, p + 1);
      else if (t < 15) { stage_K(buf ^ 1, t + 1, 0); stage_Q(qs ^ 1, 0); }
      const ushort_t* vb_ = lds + buf * 8192;
      const int dc = p >> 1, kvc = p & 1;
#pragma unroll
      for (int kc = 0; kc < 2; ++kc) {
        bf16x8 pa[2], vv[2];
#pragma unroll
        for (int mi = 0; mi < 2; ++mi) {
          const int row = wm * 32 + mi * 16 + r16;
          pa[mi] = *(const bf16x8*)
              &Pl[(row * 16 + ((kvc * 8 + kc * 4 + quad) ^ (row & 15))) << 3];
        }
#pragma unroll
        for (int ni = 0; ni < 2; ++ni) {
          const int dr = wk * 32 + ni * 16 + r16;
          vv[ni] = *(const bf16x8*)&vb_[(dr * 8 + ((kc * 4 + quad) ^ (dr & 7))) << 3];
        }
#pragma unroll
        for (int mi = 0; mi < 2; ++mi)
#pragma unroll
          for (int ni = 0; ni < 2; ++ni)
            accO[mi][dc * 2 + ni] = __builtin_amdgcn_mfma_f32_16x16x32_bf16(
                pa[mi], vv[ni], accO[mi][dc * 2 + ni], 0, 0, 0);
      }
      buf ^= 1;
    }
    qs ^= 1;
  }
  // epilogue: partial O (normalized by l), plus m,l
  ushort_t* Op = Opart + (size_t)z * 4 * 4096 * 512 + bofs;
#pragma unroll
  for (int mi = 0; mi < 2; ++mi)
#pragma unroll
    for (int rr = 0; rr < 4; ++rr) {
      const float inv = 1.f / l_i[mi][rr];
      const int row = qb0 + wm * 32 + mi * 16 + quad * 4 + rr;
      ushort_t* op = Op + (size_t)row * 512;
#pragma unroll
      for (int dc = 0; dc < 4; ++dc)
#pragma unroll
        for (int ni = 0; ni < 2; ++ni)
          op[dc * 128 + wk * 32 + ni * 16 + r16] =
              f2bf(accO[mi][dc * 2 + ni][rr] * inv);
      if (wk == 0 && r16 == 0) {
        Mp[z * 16384 + b * 4096 + row] = m_i[mi][rr];
        Lp[z * 16384 + b * 4096 + row] = l_i[mi][rr];
      }
    }
}

// merge the two kv-half partials: h = (w0*O0 + w1*O1), w_i = l_i e^{m_i-m}/Z
__global__ __launch_bounds__(128) void merge_k(
    const ushort_t* __restrict__ Opart, const float* __restrict__ Mp,
    const float* __restrict__ Lp, ushort_t* __restrict__ h) {
  const int row = blockIdx.x;  // b*4096+n, 0..16383
  const float m0 = Mp[row], m1 = Mp[16384 + row];
  const float l0 = Lp[row], l1 = Lp[16384 + row];
  const float mm = fmaxf(m0, m1);
  float w0 = __expf(m0 - mm) * l0, w1 = __expf(m1 - mm) * l1;
  const float inv = 1.f / (w0 + w1);
  w0 *= inv; w1 *= inv;
  const ushort4* a = (const ushort4*)(Opart + (size_t)row * 512);
  const ushort4* bb = (const ushort4*)(Opart + (size_t)(16384 + row) * 512);
  ushort4* o = (ushort4*)(h + (size_t)row * 512);
  const int t = threadIdx.x;
  ushort4 ua = a[t], ub = bb[t];
  ushort4 r;
  r.x = f2bf(bf2f(ua.x) * w0 + bf2f(ub.x) * w1);
  r.y = f2bf(bf2f(ua.y) * w0 + bf2f(ub.y) * w1);
  r.z = f2bf(bf2f(ua.z) * w0 + bf2f(ub.z) * w1);
  r.w = f2bf(bf2f(ua.w) * w0 + bf2f(ub.w) * w1);
  o[t] = r;
}

extern "C" void kernel_launch(void* const* d_in, const int* in_sizes, int n_in,
                              void* d_out, int out_size, void* d_ws, size_t ws_size,
                              hipStream_t stream) {
  const float* x  = (const float*)d_in[0];
  const float* gs = (const float*)d_in[1];
  const float* gb = (const float*)d_in[2];
  const float* wq = (const float*)d_in[3];
  const float* bq = (const float*)d_in[4];
  const float* wk = (const float*)d_in[5];
  const float* bk = (const float*)d_in[6];
  const float* wv = (const float*)d_in[7];
  const float* bv = (const float*)d_in[8];
  const float* wo = (const float*)d_in[9];
  const float* bo = (const float*)d_in[10];
  float* out = (float*)d_out;

  const size_t HNC = (size_t)4 * 4096 * 512;
  char* w = (char*)d_ws;
  float* stats  = (float*)w;    w += 4096;
  ushort_t* wb  = (ushort_t*)w; w += (size_t)4 * 262144 * 2;
  ushort_t* h   = (ushort_t*)w; w += HNC * 2;  // GN out; reused as merged O
  ushort_t* q   = (ushort_t*)w; w += HNC * 2;
  ushort_t* kk  = (ushort_t*)w; w += HNC * 2;
  ushort_t* vt  = (ushort_t*)w; w += HNC * 2;  // V transposed [B,C,N]
  ushort_t* op  = (ushort_t*)w; w += 2 * HNC * 2;  // partial O, 2 kv-halves
  float* Mp     = (float*)w;    w += 2 * 16384 * 4;
  float* Lp     = (float*)w;    w += 2 * 16384 * 4;

  const float sc = 0.044194173824159216f;  // 512^-0.5, folded into wq/bq

  hipFuncSetAttribute((const void*)flash_k,
                      hipFuncAttributeMaxDynamicSharedMemorySize, FLASH_LDS_BYTES);

  gn_stats_k<<<128, 256, 0, stream>>>(x, stats);
  gn_apply_k<<<8192, 256, 0, stream>>>(x, stats, gs, gb, h);
  Ptr4 wsrc;
  wsrc.src[0] = wq; wsrc.src[1] = wk; wsrc.src[2] = wv; wsrc.src[3] = wo;
  wsrc.wsc[0] = sc; wsrc.wsc[1] = 1.f; wsrc.wsc[2] = 1.f; wsrc.wsc[3] = 1.f;
  cvt_all_k<<<4096, 256, 0, stream>>>(wsrc, wb);

  Ptr3 qkv;
  qkv.bias[0] = bq; qkv.bias[1] = bk; qkv.bias[2] = bv;
  qkv.out[0] = q; qkv.out[1] = kk; qkv.out[2] = vt;
  qkv.bs[0] = sc; qkv.bs[1] = 1.f; qkv.bs[2] = 1.f;
  gemm_nt_k<128, 128, 32, 3><<<dim3(4, 128, 3), 256, 0, stream>>>(
      h, 512, wb, 512, nullptr, 0, nullptr, nullptr, 1.f, 512,
      0, 262144, 0, qkv);

  flash_k<<<dim3(64, 4, 2), 512, FLASH_LDS_BYTES, stream>>>(q, kk, vt, op, Mp, Lp);
  merge_k<<<16384, 128, 0, stream>>>(op, Mp, Lp, h);

  Ptr3 e0{};
  gemm_nt_k<128, 128, 32, 2><<<dim3(4, 128, 1), 256, 0, stream>>>(
      h, 512, wb + (size_t)3 * 262144, 512, out, 512, bo, x, 1.f, 512,
      0, 0, 0, e0);
}

// Round 7
// 418.684 us; speedup vs baseline: 2.0089x; 1.3835x over previous
//
#include <hip/hip_runtime.h>
#include <cstdint>
#include <cstddef>

typedef unsigned short ushort_t;
typedef __attribute__((ext_vector_type(8))) __bf16 bf16x8;
typedef __attribute__((ext_vector_type(4))) float f32x4;

#define DEVINL __device__ __forceinline__

DEVINL ushort_t f2bf(float f) {
  union { float f; unsigned u; } v; v.f = f;
  unsigned r = (v.u + 0x7fffu + ((v.u >> 16) & 1u)) >> 16;
  return (ushort_t)r;
}
DEVINL float bf2f(ushort_t u) {
  union { unsigned u; float f; } v; v.u = ((unsigned)u) << 16;
  return v.f;
}

DEVINL float wred_sum(float x) {
#pragma unroll
  for (int o = 32; o > 0; o >>= 1) x += __shfl_xor(x, o, 64);
  return x;
}

// async global->LDS, 16B per lane (global_load_lds_dwordx4)
DEVINL void async16(ushort_t* lds, const ushort_t* g) {
  __builtin_amdgcn_global_load_lds(
      (__attribute__((address_space(1))) const unsigned int*)g,
      (__attribute__((address_space(3))) unsigned int*)lds, 16, 0, 0);
}

template <int CPR>
DEVINL int fswz(int r) {
  if constexpr (CPR == 4) return (r >> 2) & 3;
  else return r & 7;  // CPR==8
}

// ---------------- GroupNorm ----------------
__global__ __launch_bounds__(256) void gn_stats_k(const float* __restrict__ x,
                                                  float* __restrict__ stats) {
  const int bg = blockIdx.x;
  const float4* base = (const float4*)(x + ((size_t)bg << 16));
  float s = 0.f, q = 0.f;
  for (int i = threadIdx.x; i < 16384; i += 256) {
    float4 f = base[i];
    s += f.x + f.y + f.z + f.w;
    q += f.x * f.x + f.y * f.y + f.z * f.z + f.w * f.w;
  }
  s = wred_sum(s);
  q = wred_sum(q);
  __shared__ float rs[4], rq[4];
  const int lane = threadIdx.x & 63, wid = threadIdx.x >> 6;
  if (lane == 0) { rs[wid] = s; rq[wid] = q; }
  __syncthreads();
  if (threadIdx.x == 0) {
    float S = rs[0] + rs[1] + rs[2] + rs[3];
    float Q = rq[0] + rq[1] + rq[2] + rq[3];
    float mean = S * (1.f / 65536.f);
    float var = Q * (1.f / 65536.f) - mean * mean;
    stats[2 * bg] = mean;
    stats[2 * bg + 1] = rsqrtf(var + 1e-5f);
  }
}

__global__ __launch_bounds__(256) void gn_apply_k(const float* __restrict__ x,
                                                  const float* __restrict__ stats,
                                                  const float* __restrict__ gs,
                                                  const float* __restrict__ gb,
                                                  ushort_t* __restrict__ h) {
  __shared__ ushort_t tile[32][33];
  const int bid = blockIdx.x;
  const int b = bid >> 11;
  const int r = bid & 2047;
  const int ct = r >> 7, nt = r & 127;
  const int c0 = ct << 5, n0 = nt << 5;
  const int tx = threadIdx.x & 31, ty = threadIdx.x >> 5;
#pragma unroll
  for (int i = 0; i < 4; ++i) {
    const int c = c0 + ty + i * 8;
    const float mean = stats[2 * (b * 32 + (c >> 4))];
    const float rstd = stats[2 * (b * 32 + (c >> 4)) + 1];
    const float xv = x[(((size_t)b * 512 + c) << 12) + n0 + tx];
    tile[ty + i * 8][tx] = f2bf((xv - mean) * rstd * gs[c] + gb[c]);
  }
  __syncthreads();
#pragma unroll
  for (int i = 0; i < 4; ++i) {
    const int n = n0 + ty + i * 8;
    h[(((size_t)b << 12) + n) * 512 + c0 + tx] = tile[tx][ty + i * 8];
  }
}

// fp32 -> bf16 convert with per-matrix scale (sc folded into wq)
struct Ptr4 { const float* src[4]; float wsc[4]; };
__global__ __launch_bounds__(256) void cvt_all_k(Ptr4 s, ushort_t* __restrict__ dst) {
  const int i = blockIdx.x * 256 + threadIdx.x;
  const int m = i >> 18;
  dst[i] = f2bf(s.src[m][i & 262143] * s.wsc[m]);
}

// ---------------- NT GEMM: C[M,N] = A[M,K] * B[N,K]^T ----------------
// EPI 2: fp32 transposed out + resid + bias (final projection).
// EPI 3: QKV fused, z picks weight/bias/out; z==2 (V) writes transposed [C][N].
// EPI 4: scores -> exp(acc) as bf16 + atomic per-row sum into lbuf[z*4096+row].
// EPI 5: PV -> acc / lbuf[z*4096+row], bf16 out.
struct Ptr3 { const float* bias[3]; ushort_t* out[3]; float bs[3]; };

template <int BM, int BN, int BK, int EPI>
__global__ __launch_bounds__(256) void gemm_nt_k(
    const ushort_t* __restrict__ A, int lda, const ushort_t* __restrict__ Bm, int ldb,
    void* __restrict__ Cout, int ldc, const float* __restrict__ bias,
    const float* __restrict__ resid, float scale, int K,
    size_t azs, size_t bzs, size_t czs, Ptr3 p3, float* __restrict__ lbuf) {
  constexpr int CPR = BK / 8;
  constexpr int WTM = BM / 2, WTN = BN / 2;
  constexpr int MI = WTM / 16, NI = WTN / 16;
  constexpr int AR = (BM * CPR) / 256;
  constexpr int BR = (BN * CPR) / 256;
  __shared__ ushort_t Als[BM * BK];
  __shared__ ushort_t Bls[BN * BK];
  const int tid = threadIdx.x;
  const int lane = tid & 63;
  const int wid = tid >> 6;
  const int quad = lane >> 4;
  const int r16 = lane & 15;
  const int wm = wid >> 1, wn = wid & 1;
  const int m0 = blockIdx.y * BM;
  const int n0 = blockIdx.x * BN;
  const int zb = blockIdx.z;

  A += azs * zb;
  Bm += bzs * zb;

  f32x4 acc[MI][NI] = {};

  for (int kt = 0; kt < K; kt += BK) {
#pragma unroll
    for (int r = 0; r < AR; ++r) {
      const int s = r * 256 + tid;
      const int row = s / CPR;
      const int q = (s % CPR) ^ fswz<CPR>(row);
      async16(&Als[s << 3], A + (size_t)(m0 + row) * lda + kt + (q << 3));
    }
#pragma unroll
    for (int r = 0; r < BR; ++r) {
      const int s = r * 256 + tid;
      const int row = s / CPR;
      const int q = (s % CPR) ^ fswz<CPR>(row);
      async16(&Bls[s << 3], Bm + (size_t)(n0 + row) * ldb + kt + (q << 3));
    }
    __syncthreads();
#pragma unroll
    for (int kf = 0; kf < BK / 32; ++kf) {
      bf16x8 af[MI], bfr[NI];
#pragma unroll
      for (int mi = 0; mi < MI; ++mi) {
        const int lr = wm * WTM + mi * 16 + r16;
        const int ch = kf * 4 + quad;
        af[mi] = *reinterpret_cast<const bf16x8*>(
            &Als[(lr * CPR + (ch ^ fswz<CPR>(lr))) << 3]);
      }
#pragma unroll
      for (int ni = 0; ni < NI; ++ni) {
        const int lr = wn * WTN + ni * 16 + r16;
        const int ch = kf * 4 + quad;
        bfr[ni] = *reinterpret_cast<const bf16x8*>(
            &Bls[(lr * CPR + (ch ^ fswz<CPR>(lr))) << 3]);
      }
#pragma unroll
      for (int mi = 0; mi < MI; ++mi)
#pragma unroll
        for (int ni = 0; ni < NI; ++ni)
          acc[mi][ni] = __builtin_amdgcn_mfma_f32_16x16x32_bf16(
              af[mi], bfr[ni], acc[mi][ni], 0, 0, 0);
    }
    __syncthreads();
  }

  const int mrow = m0 + wm * WTM;
  const int ncol = n0 + wn * WTN;
  if constexpr (EPI == 2) {  // final: fp32 transposed out + resid + bias
    float* C = (float*)Cout;
#pragma unroll
    for (int ni = 0; ni < NI; ++ni) {
      const int col = ncol + ni * 16 + r16;
      const float bvv = bias[col];
#pragma unroll
      for (int mi = 0; mi < MI; ++mi) {
        const int rowb = mrow + mi * 16 + quad * 4;
        const int bb = rowb >> 12;
        const int nl = rowb & 4095;
        const size_t base = (((size_t)bb * 512 + col) << 12) + nl;
        const float4 rv = *(const float4*)&resid[base];
        float4 ov;
        ov.x = rv.x + acc[mi][ni][0] + bvv;
        ov.y = rv.y + acc[mi][ni][1] + bvv;
        ov.z = rv.z + acc[mi][ni][2] + bvv;
        ov.w = rv.w + acc[mi][ni][3] + bvv;
        *(float4*)&C[base] = ov;
      }
    }
  } else if constexpr (EPI == 3) {  // QKV, z picks weight/bias/out; z==2 V^T
    const float* bz = p3.bias[zb];
    const float bsc = p3.bs[zb];
    ushort_t* O = p3.out[zb];
    if (zb < 2) {
#pragma unroll
      for (int ni = 0; ni < NI; ++ni) {
        const int col = ncol + ni * 16 + r16;
        const float bvv = bz[col] * bsc;
#pragma unroll
        for (int mi = 0; mi < MI; ++mi) {
          const int rowb = mrow + mi * 16 + quad * 4;
#pragma unroll
          for (int rr = 0; rr < 4; ++rr)
            O[(size_t)(rowb + rr) * 512 + col] = f2bf(acc[mi][ni][rr] + bvv);
        }
      }
    } else {
#pragma unroll
      for (int ni = 0; ni < NI; ++ni) {
        const int col = ncol + ni * 16 + r16;
        const float bvv = bz[col];
#pragma unroll
        for (int mi = 0; mi < MI; ++mi) {
          const int rowb = mrow + mi * 16 + quad * 4;
          const int bb = rowb >> 12;
          const int nn = rowb & 4095;
          ushort4 pk;
          pk.x = f2bf(acc[mi][ni][0] + bvv);
          pk.y = f2bf(acc[mi][ni][1] + bvv);
          pk.z = f2bf(acc[mi][ni][2] + bvv);
          pk.w = f2bf(acc[mi][ni][3] + bvv);
          *(ushort4*)&O[(((size_t)bb * 512 + col) << 12) + nn] = pk;
        }
      }
    }
  } else if constexpr (EPI == 4) {  // scores: exp + bf16 + atomic row sum
    ushort_t* C = (ushort_t*)Cout + czs * zb;
    float* Lz = lbuf + (size_t)zb * 4096;
#pragma unroll
    for (int mi = 0; mi < MI; ++mi) {
#pragma unroll
      for (int rr = 0; rr < 4; ++rr) {
        const int row = mrow + mi * 16 + quad * 4 + rr;
        float ps = 0.f;
#pragma unroll
        for (int ni = 0; ni < NI; ++ni) {
          const int col = ncol + ni * 16 + r16;
          const ushort_t ub = f2bf(__expf(acc[mi][ni][rr]));
          C[(size_t)row * ldc + col] = ub;
          ps += bf2f(ub);  // sum the ROUNDED values so l matches PV's MFMA sum
        }
#pragma unroll
        for (int o = 1; o < 16; o <<= 1) ps += __shfl_xor(ps, o, 64);
        if (r16 == 0) atomicAdd(&Lz[row], ps);
      }
    }
  } else {  // EPI == 5: PV, divide by row sum, bf16 out
    ushort_t* C = (ushort_t*)Cout + czs * zb;
    const float* Lz = lbuf + (size_t)zb * 4096;
#pragma unroll
    for (int mi = 0; mi < MI; ++mi) {
#pragma unroll
      for (int rr = 0; rr < 4; ++rr) {
        const int row = mrow + mi * 16 + quad * 4 + rr;
        const float inv = 1.f / Lz[row];
#pragma unroll
        for (int ni = 0; ni < NI; ++ni) {
          const int col = ncol + ni * 16 + r16;
          C[(size_t)row * ldc + col] = f2bf(acc[mi][ni][rr] * inv);
        }
      }
    }
  }
}

extern "C" void kernel_launch(void* const* d_in, const int* in_sizes, int n_in,
                              void* d_out, int out_size, void* d_ws, size_t ws_size,
                              hipStream_t stream) {
  const float* x  = (const float*)d_in[0];
  const float* gs = (const float*)d_in[1];
  const float* gb = (const float*)d_in[2];
  const float* wq = (const float*)d_in[3];
  const float* bq = (const float*)d_in[4];
  const float* wk = (const float*)d_in[5];
  const float* bk = (const float*)d_in[6];
  const float* wv = (const float*)d_in[7];
  const float* bv = (const float*)d_in[8];
  const float* wo = (const float*)d_in[9];
  const float* bo = (const float*)d_in[10];
  float* out = (float*)d_out;

  const size_t HNC = (size_t)4 * 4096 * 512;
  char* w = (char*)d_ws;
  float* stats  = (float*)w;    w += 4096;
  float* Ls     = (float*)w;    w += (size_t)4 * 4096 * 4;  // exp row sums
  ushort_t* wb  = (ushort_t*)w; w += (size_t)4 * 262144 * 2;
  ushort_t* h   = (ushort_t*)w; w += HNC * 2;  // GN out; reused as O
  ushort_t* q   = (ushort_t*)w; w += HNC * 2;
  ushort_t* kk  = (ushort_t*)w; w += HNC * 2;
  ushort_t* vt  = (ushort_t*)w; w += HNC * 2;  // V transposed [B,C,N]
  ushort_t* Se  = (ushort_t*)w; w += (size_t)4 * 4096 * 4096 * 2;  // exp(S) bf16

  const float sc = 0.044194173824159216f;  // 512^-0.5, folded into wq/bq

  gn_stats_k<<<128, 256, 0, stream>>>(x, stats);
  gn_apply_k<<<8192, 256, 0, stream>>>(x, stats, gs, gb, h);
  Ptr4 wsrc;
  wsrc.src[0] = wq; wsrc.src[1] = wk; wsrc.src[2] = wv; wsrc.src[3] = wo;
  wsrc.wsc[0] = sc; wsrc.wsc[1] = 1.f; wsrc.wsc[2] = 1.f; wsrc.wsc[3] = 1.f;
  cvt_all_k<<<4096, 256, 0, stream>>>(wsrc, wb);
  hipMemsetAsync(Ls, 0, (size_t)4 * 4096 * 4, stream);

  Ptr3 qkv;
  qkv.bias[0] = bq; qkv.bias[1] = bk; qkv.bias[2] = bv;
  qkv.out[0] = q; qkv.out[1] = kk; qkv.out[2] = vt;
  qkv.bs[0] = sc; qkv.bs[1] = 1.f; qkv.bs[2] = 1.f;
  gemm_nt_k<128, 128, 32, 3><<<dim3(4, 128, 3), 256, 0, stream>>>(
      h, 512, wb, 512, nullptr, 0, nullptr, nullptr, 1.f, 512,
      0, 262144, 0, qkv, nullptr);

  Ptr3 e0{};
  // Se[z] = exp(q k^T) bf16, plus atomic row sums into Ls
  gemm_nt_k<128, 128, 64, 4><<<dim3(32, 32, 4), 256, 0, stream>>>(
      q, 512, kk, 512, Se, 4096, nullptr, nullptr, 1.f, 512,
      (size_t)4096 * 512, (size_t)4096 * 512, (size_t)4096 * 4096, e0, Ls);
  // O[z] = (Se V) / l, bf16 into h
  gemm_nt_k<128, 128, 64, 5><<<dim3(4, 32, 4), 256, 0, stream>>>(
      Se, 4096, vt, 4096, h, 512, nullptr, nullptr, 1.f, 4096,
      (size_t)4096 * 4096, (size_t)512 * 4096, (size_t)4096 * 512, e0, Ls);

  // out = x + O @ wo^T + bo, transposed back to [B,C,H,W]
  gemm_nt_k<128, 128, 32, 2><<<dim3(4, 128, 1), 256, 0, stream>>>(
      h, 512, wb + (size_t)3 * 262144, 512, out, 512, bo, x, 1.f, 512,
      0, 0, 0, e0, nullptr);
}